// Round 17
// baseline (486.382 us; speedup 1.0000x reference)
//
#include <hip/hip_runtime.h>
#include <math.h>

#define BATCH 16384
#define EPSQ 1e-8f

// ---------------- ws layout (32-bit units) ----------------
#define OFF_SCAL 0
#define OFF_WPK1 16        // 180 u32
#define OFF_WPK2 196       // 960 u32
#define OFF_FQ1  1156      // 12000 u32
#define OFF_FQ2  13156     // 2688 u32
#define OFF_FQ3  15844     // 240 u32
#define OFF_A    16384
#define OFF_QIN   OFF_A                 // [B][3][32slots][48] i8 quant1->conv1
#define OFF_ISUM2 (OFF_A + 6400000)     // [B][400] i16 conv2->fc1
#define OFF_P3    (OFF_A + 12000000)    // [B][120] f32 fc1->fc2
#define OFF_P4    (OFF_A + 14000000)    // [B][84]  f32 fc2->fc3
#define OFF_ISUM1 (OFF_A + 18874368)    // [B][1176] i16 conv1->conv2

__device__ inline int sdot4(unsigned int a, unsigned int b, int c) {
    return __builtin_amdgcn_sdot4((int)a, (int)b, c, false);
}

__device__ inline unsigned int fkey(float f) {
    unsigned int u = __float_as_uint(f);
    return (u & 0x80000000u) ? ~u : (u | 0x80000000u);
}
__device__ inline float fdec(unsigned int k) {
    unsigned int u = (k & 0x80000000u) ? (k ^ 0x80000000u) : ~k;
    return __uint_as_float(u);
}
#define KEY_ZERO   0x80000000u
#define KEY_NEGINF 0x007FFFFFu

__device__ inline float waveMax(float v) {
    #pragma unroll
    for (int off = 32; off > 0; off >>= 1)
        v = fmaxf(v, __shfl_down(v, off, 64));
    return v;
}

__device__ inline void blockAtomicMax2(float vmax, float vnmax,
                                       unsigned int* gmax, unsigned int* gnmax) {
    __shared__ float sm[4], sn[4];
    float a = waveMax(vmax), b = waveMax(vnmax);
    int tid = threadIdx.x;
    if ((tid & 63) == 0) { sm[tid >> 6] = a; sn[tid >> 6] = b; }
    __syncthreads();
    if (tid == 0) {
        atomicMax(gmax, fkey(fmaxf(fmaxf(sm[0], sm[1]), fmaxf(sm[2], sm[3]))));
        atomicMax(gnmax, fkey(fmaxf(fmaxf(sn[0], sn[1]), fmaxf(sn[2], sn[3]))));
    }
}

__device__ inline float fq_elem(float x, float s) {
    float q = fminf(fmaxf(rintf(x / s), -128.0f), 127.0f);
    return q * s;
}
__device__ inline int qrelu_code(float x, float s1, float s2) {
    float q = fq_elem(x, s1);
    q = fmaxf(q, 0.0f);
    return (int)fminf(fmaxf(rintf(q / s2), -128.0f), 127.0f);
}
__device__ inline void get_qrelu_scales(const unsigned int* scalu, int slot,
                                        float& s1, float& s2) {
    float maxa = fdec(scalu[slot]), negm = fdec(scalu[slot + 1]);
    float absm = fmaxf(maxa, negm);
    s1 = fmaxf(absm / 127.0f, EPSQ);
    float qm = fminf(fmaxf(rintf(maxa / s1), -128.0f), 127.0f) * s1;
    s2 = fmaxf(fmaxf(qm, 0.0f) / 127.0f, EPSQ);
}

__device__ inline unsigned int sgn8(float w) { return (w >= 0.0f) ? 0x01u : 0xFFu; }

__device__ inline unsigned int u32at(const unsigned int* wv, int wi, int k) {
    return (k == 0) ? wv[wi]
        : __builtin_amdgcn_perm(wv[wi + 1], wv[wi], 0x03020100u + 0x01010101u * (unsigned)k);
}

// ---------------- prep ----------------
__global__ __launch_bounds__(256) void prep_kernel(const float* __restrict__ w1,
        const float* __restrict__ w2, const float* __restrict__ fw1,
        const float* __restrict__ fw2, const float* __restrict__ fw3,
        float* __restrict__ wsf) {
    int blk = blockIdx.x, tid = threadIdx.x;
    unsigned int* wsu = (unsigned int*)wsf;
    if (blk == 0) {
        if (tid == 0) wsu[0] = KEY_ZERO;
        else if (tid <= 8) wsu[tid] = KEY_NEGINF;
        return;
    }
    const float* src = nullptr; int N = 0;
    if (blk == 1)      { src = w1;  N = 450; }
    else if (blk == 2) { src = w2;  N = 2400; }
    else if (blk == 3) { src = fw1; N = 48000; }
    else if (blk == 4) { src = fw2; N = 10080; }
    else               { src = fw3; N = 840; }
    __shared__ float red[256];
    float partial = 0.0f;
    for (int i = tid; i < N; i += 256) partial += fabsf(src[i]);
    red[tid] = partial;
    __syncthreads();
    for (int s = 128; s > 0; s >>= 1) {
        if (tid < s) red[tid] += red[tid + s];
        __syncthreads();
    }
    if (tid == 0) wsf[8 + blk] = red[0] / (float)N;

    if (blk == 1) {
        for (int t = tid; t < 90; t += 256) {
            const float* wp = w1 + t * 5;
            wsu[OFF_WPK1 + 2*t] = sgn8(wp[0]) | (sgn8(wp[1])<<8) | (sgn8(wp[2])<<16) | (sgn8(wp[3])<<24);
            wsu[OFF_WPK1 + 2*t + 1] = sgn8(wp[4]) << 24;
        }
    } else if (blk == 2) {
        for (int t = tid; t < 480; t += 256) {
            const float* wp = w2 + t * 5;
            wsu[OFF_WPK2 + 2*t] = sgn8(wp[0]) | (sgn8(wp[1])<<8) | (sgn8(wp[2])<<16) | (sgn8(wp[3])<<24);
            wsu[OFF_WPK2 + 2*t + 1] = sgn8(wp[4]) << 24;
        }
    } else if (blk == 3) {
        for (int i = tid; i < 12000; i += 256) {
            int j = i / 100, k = i % 100;
            const float* wp = fw1 + j * 400 + k * 4;
            wsu[OFF_FQ1 + i] = sgn8(wp[0]) | (sgn8(wp[1])<<8) | (sgn8(wp[2])<<16) | (sgn8(wp[3])<<24);
        }
    } else if (blk == 4) {
        for (int i = tid; i < 2688; i += 256) {
            int j = i >> 5, k = i & 31;
            unsigned int u = 0;
            if (k < 30) {
                const float* wp = fw2 + j * 120 + k * 4;
                u = sgn8(wp[0]) | (sgn8(wp[1])<<8) | (sgn8(wp[2])<<16) | (sgn8(wp[3])<<24);
            }
            wsu[OFF_FQ2 + i] = u;
        }
    } else {
        for (int i = tid; i < 240; i += 256) {
            int j = i / 24, k = i % 24;
            unsigned int u = 0;
            if (k < 21) {
                const float* wp = fw3 + j * 84 + k * 4;
                u = sgn8(wp[0]) | (sgn8(wp[1])<<8) | (sgn8(wp[2])<<16) | (sgn8(wp[3])<<24);
            }
            wsu[OFF_FQ3 + i] = u;
        }
    }
}

// ---------------- input abs-max ----------------
__global__ __launch_bounds__(256) void absmax_kernel(const float4* __restrict__ x, int n4,
                                                     unsigned int* __restrict__ gkey) {
    float m = 0.0f;
    int stride = gridDim.x * 256;
    for (int i = blockIdx.x * 256 + threadIdx.x; i < n4; i += stride) {
        float4 v = x[i];
        m = fmaxf(m, fmaxf(fmaxf(fabsf(v.x), fabsf(v.y)), fmaxf(fabsf(v.z), fabsf(v.w))));
    }
    __shared__ float sm[4];
    m = waveMax(m);
    int tid = threadIdx.x;
    if ((tid & 63) == 0) sm[tid >> 6] = m;
    __syncthreads();
    if (tid == 0)
        atomicMax(gkey, fkey(fmaxf(fmaxf(sm[0], sm[1]), fmaxf(sm[2], sm[3]))));
}

// ---------------- quant1: fp32 -> i8 codes, row-interleaved [B][3][slot(32)][48] ----
__global__ __launch_bounds__(256) void quant1_kernel(const float4* __restrict__ x,
                                                     float* __restrict__ wsf) {
    unsigned int* wsu = (unsigned int*)wsf;
    float s0 = fmaxf(fdec(wsu[0]) / 127.0f, EPSQ);
    unsigned int* qin = wsu + OFF_QIN;
    int stride = gridDim.x * 256;
    const int total = BATCH * 96 * 12;
    for (int unit = blockIdx.x * 256 + threadIdx.x; unit < total; unit += stride) {
        int row_id = unit / 12, w = unit % 12;
        int plane = row_id >> 5, row = row_id & 31;
        int slot = (row >> 1) + ((row & 1) << 4);
        unsigned int u = 0;
        if (w < 8) {
            float4 v = x[row_id * 8 + w];
            int q0 = (int)fminf(fmaxf(rintf(v.x / s0), -128.f), 127.f);
            int q1 = (int)fminf(fmaxf(rintf(v.y / s0), -128.f), 127.f);
            int q2 = (int)fminf(fmaxf(rintf(v.z / s0), -128.f), 127.f);
            int q3 = (int)fminf(fmaxf(rintf(v.w / s0), -128.f), 127.f);
            u = (q0 & 255) | ((q1 & 255) << 8) | ((q2 & 255) << 16) | ((unsigned)(q3 & 255) << 24);
        }
        qin[(plane * 32 + slot) * 12 + w] = u;
    }
}

// ---------------- conv1: 8 img/block, 1 ch/thread, interleaved rows, dot4 ------
#define C1_ROWP 48
#define C1_CIS  1536
#define C1_IMGS 4608
#define C1_NIMG 8

template<int PH>
__device__ __forceinline__ void c1_phase(const unsigned char* ib, const unsigned int* wcp,
                                         int* ip, int& gmax, int& gmin) {
    int a0[14], a1[14];
    #pragma unroll
    for (int i = 0; i < 14; i++) { a0[i] = 0; a1[i] = 0; }
    #pragma unroll 1
    for (int ci = 0; ci < 3; ci++) {
        uint4 A[6]; unsigned int Bv[6];
        const unsigned char* cb = ib + ci * C1_CIS;
        #pragma unroll
        for (int r = 0; r < 6; r++) {
            const unsigned char* rb = cb + (((r & 1) << 4) + (r >> 1)) * C1_ROWP;
            if (PH == 0) {
                A[r]  = *(const uint4*)(rb);
                Bv[r] = *(const unsigned int*)(rb + 16);
            } else {
                Bv[r] = *(const unsigned int*)(rb + 12);
                A[r]  = *(const uint4*)(rb + 16);
            }
        }
        const unsigned int* wkp = wcp + ci * 10;
        unsigned int wk0[5], wk4[5];
        #pragma unroll
        for (int ky = 0; ky < 5; ky++) { wk0[ky] = wkp[2*ky]; wk4[ky] = wkp[2*ky+1]; }
        #pragma unroll
        for (int r6 = 0; r6 < 6; r6++) {
            unsigned int wv[5];
            if (PH == 0) {
                wv[0] = A[r6].x; wv[1] = A[r6].y; wv[2] = A[r6].z; wv[3] = A[r6].w; wv[4] = Bv[r6];
            } else {
                wv[0] = Bv[r6]; wv[1] = A[r6].x; wv[2] = A[r6].y; wv[3] = A[r6].z; wv[4] = A[r6].w;
            }
            const int OFS = (PH == 0) ? 0 : 2;
            unsigned int up[15];
            #pragma unroll
            for (int i = 0; i < 15; i++) {
                int e = OFS + i;
                up[i] = u32at(wv, e >> 2, e & 3);
            }
            if (r6 <= 4) {
                unsigned int w0 = wk0[r6], w4 = wk4[r6];
                #pragma unroll
                for (int i = 0; i < 14; i++) {
                    a0[i] = sdot4(up[i], w0, a0[i]);
                    a0[i] = sdot4(up[i+1], w4, a0[i]);
                }
            }
            if (r6 >= 1) {
                unsigned int w0 = wk0[r6-1], w4 = wk4[r6-1];
                #pragma unroll
                for (int i = 0; i < 14; i++) {
                    a1[i] = sdot4(up[i], w0, a1[i]);
                    a1[i] = sdot4(up[i+1], w4, a1[i]);
                }
            }
        }
    }
    #pragma unroll
    for (int i = 0; i < 14; i++) {
        gmax = max(gmax, max(a0[i], a1[i]));
        gmin = min(gmin, min(a0[i], a1[i]));
    }
    #pragma unroll
    for (int p = 0; p < 7; p++)
        ip[p] = max(max(a0[2*p], a0[2*p+1]), max(a1[2*p], a1[2*p+1]));
}

__global__ __launch_bounds__(256) void conv1_kernel(const float* __restrict__ b1,
                                                    float* __restrict__ wsf) {
    __shared__ __align__(16) unsigned char xq[C1_NIMG * C1_IMGS];   // 36864 B
    __shared__ unsigned int wpk[180];
    __shared__ float bsm[6];
    unsigned int* wsu = (unsigned int*)wsf;
    int tid = threadIdx.x;
    int b0 = blockIdx.x * C1_NIMG;   // BATCH % 8 == 0
    float s0 = fmaxf(fdec(wsu[0]) / 127.0f, EPSQ);
    float seff = s0 * wsf[9];

    {
        const uint4* src = (const uint4*)((const unsigned char*)(wsu + OFF_QIN) + (size_t)b0 * C1_IMGS);
        uint4* dst = (uint4*)xq;
        for (int i = tid; i < C1_NIMG * 288; i += 256) dst[i] = src[i];
    }
    for (int i = tid; i < 180; i += 256) wpk[i] = wsu[OFF_WPK1 + i];
    if (tid < 6) bsm[tid] = b1[tid];
    __syncthreads();

    unsigned int* isum1 = wsu + OFF_ISUM1;
    float vmax = -INFINITY, vnmax = -INFINITY;
    const int ntask = C1_NIMG * 84;  // 672
    for (int t = tid; t < ntask; t += 256) {
        int img = t / 84, r = t % 84;
        int c = r / 14, py = r % 14;
        const unsigned char* ib = &xq[img * C1_IMGS + py * C1_ROWP];
        const unsigned int* wcp = &wpk[c * 30];
        int ip0[7], ip1[7];
        int gmax = -2000000000, gmin = 2000000000;
        c1_phase<0>(ib, wcp, ip0, gmax, gmin);
        c1_phase<1>(ib, wcp, ip1, gmax, gmin);
        float bias = bsm[c];
        vmax  = fmaxf(vmax,  fmaf(seff, (float)gmax, bias));
        vnmax = fmaxf(vnmax, -fmaf(seff, (float)gmin, bias));
        unsigned int* dst = isum1 + 588 * (size_t)(b0 + img) + 7 * (c * 14 + py);
        int v14[14];
        #pragma unroll
        for (int p = 0; p < 7; p++) { v14[p] = ip0[p]; v14[7 + p] = ip1[p]; }
        #pragma unroll
        for (int p = 0; p < 7; p++)
            dst[p] = (v14[2*p] & 0xFFFF) | ((unsigned)(v14[2*p+1] & 0xFFFF) << 16);
    }
    blockAtomicMax2(vmax, vnmax, wsu + 1, wsu + 2);
}

// ---------------- conv2: 12 img/block, fused quant staging, 4 ch/thread, dot4 ------
#define C2_ROWP 16
#define C2_CIS  256
#define C2_IMGS 1536
#define C2_NIMG 12

__global__ __launch_bounds__(256) void conv2_kernel(const float* __restrict__ b1,
                                                    const float* __restrict__ b2,
                                                    float* __restrict__ wsf) {
    __shared__ __align__(16) unsigned char act[C2_NIMG * C2_IMGS];  // 18432 B
    __shared__ unsigned int wpk[960];
    __shared__ float bsm[16];
    __shared__ float b1s[6];
    __shared__ __align__(16) short spb[C2_NIMG * 400];               // 9600 B
    unsigned int* wsu = (unsigned int*)wsf;
    int tid = threadIdx.x;
    int b0 = blockIdx.x * C2_NIMG;
    int nimg = min(C2_NIMG, BATCH - b0);
    float s1, s2;
    get_qrelu_scales(wsu, 1, s1, s2);      // conv1-output qrelu scales
    float s0 = fmaxf(fdec(wsu[0]) / 127.0f, EPSQ);
    float seff1 = s0 * wsf[9];             // conv1 isum -> preact scale
    float seff = s2 * wsf[10];             // conv2 isum -> preact scale
    if (tid < 6) b1s[tid] = b1[tid];
    if (tid < 16) bsm[tid] = b2[tid];
    for (int i = tid; i < 960; i += 256) wpk[i] = wsu[OFF_WPK2 + i];
    __syncthreads();

    // fused quant2: read conv1 isum (i16), qrelu to codes, write interleaved LDS
    {
        const short* isum1 = (const short*)(wsu + OFF_ISUM1);
        for (int i = tid; i < nimg * 588; i += 256) {
            int img = i / 588, rem = i % 588;
            int e = rem * 2;
            int ci = e / 196, r2 = e % 196;
            int row = r2 / 14, col = r2 % 14;
            const short* sp = isum1 + (size_t)(b0 + img) * 1176 + e;
            float bias = b1s[ci];
            int r0 = qrelu_code(fmaf(seff1, (float)sp[0], bias), s1, s2);
            int r1 = qrelu_code(fmaf(seff1, (float)sp[1], bias), s1, s2);
            int slot = (row >> 1) + ((row & 1) << 3);
            *(unsigned short*)&act[img * C2_IMGS + ci * C2_CIS + slot * C2_ROWP + col] =
                (unsigned short)(r0 | (r1 << 8));
        }
    }
    __syncthreads();

    float vmax = -INFINITY, vnmax = -INFINITY;
    int ntask = nimg * 20;
    if (tid < ntask) {
        int img = tid / 20, rem = tid % 20;
        int cq = rem / 5, py = rem % 5;
        int c0 = cq * 4;
        const unsigned char* ib = &act[img * C2_IMGS + py * C2_ROWP];
        int a0[4][10], a1[4][10];
        #pragma unroll
        for (int cc = 0; cc < 4; cc++)
            #pragma unroll
            for (int i = 0; i < 10; i++) { a0[cc][i] = 0; a1[cc][i] = 0; }
        #pragma unroll 1
        for (int ci = 0; ci < 6; ci++) {
            uint4 R[6];
            #pragma unroll
            for (int r6 = 0; r6 < 6; r6++)
                R[r6] = *(const uint4*)(ib + ci * C2_CIS + (((r6 & 1) << 3) + (r6 >> 1)) * C2_ROWP);
            #pragma unroll
            for (int r6 = 0; r6 < 6; r6++) {
                unsigned int wv[4] = { R[r6].x, R[r6].y, R[r6].z, R[r6].w };
                unsigned int up[11];
                #pragma unroll
                for (int i = 0; i < 11; i++) up[i] = u32at(wv, i >> 2, i & 3);
                #pragma unroll
                for (int cc = 0; cc < 4; cc++) {
                    const unsigned int* wkp = &wpk[((c0 + cc) * 6 + ci) * 10];
                    if (r6 <= 4) {
                        unsigned int w0 = wkp[2 * r6], w4 = wkp[2 * r6 + 1];
                        #pragma unroll
                        for (int i = 0; i < 10; i++) {
                            a0[cc][i] = sdot4(up[i], w0, a0[cc][i]);
                            a0[cc][i] = sdot4(up[i + 1], w4, a0[cc][i]);
                        }
                    }
                    if (r6 >= 1) {
                        unsigned int w0 = wkp[2 * (r6 - 1)], w4 = wkp[2 * (r6 - 1) + 1];
                        #pragma unroll
                        for (int i = 0; i < 10; i++) {
                            a1[cc][i] = sdot4(up[i], w0, a1[cc][i]);
                            a1[cc][i] = sdot4(up[i + 1], w4, a1[cc][i]);
                        }
                    }
                }
            }
        }
        #pragma unroll
        for (int cc = 0; cc < 4; cc++) {
            int gmax = -2000000000, gmin = 2000000000;
            #pragma unroll
            for (int i = 0; i < 10; i++) {
                gmax = max(gmax, max(a0[cc][i], a1[cc][i]));
                gmin = min(gmin, min(a0[cc][i], a1[cc][i]));
            }
            float bias = bsm[c0 + cc];
            vmax  = fmaxf(vmax,  fmaf(seff, (float)gmax, bias));
            vnmax = fmaxf(vnmax, -fmaf(seff, (float)gmin, bias));
            short* dst = spb + img * 400 + (c0 + cc) * 25 + py * 5;
            #pragma unroll
            for (int p = 0; p < 5; p++)
                dst[p] = (short)max(max(a0[cc][2*p], a0[cc][2*p+1]),
                                    max(a1[cc][2*p], a1[cc][2*p+1]));
        }
    }
    __syncthreads();
    {
        const uint4* pb4 = (const uint4*)spb;
        uint4* d4 = (uint4*)((short*)(wsu + OFF_ISUM2) + (size_t)b0 * 400);
        for (int i = tid; i < nimg * 50; i += 256) d4[i] = pb4[i];
    }
    blockAtomicMax2(vmax, vnmax, wsu + 3, wsu + 4);
}

// ---------------- fc1: fused quant staging, 32 rows/block (512 blocks) ----------------
__global__ __launch_bounds__(256) void fc1_kernel(const float* __restrict__ b2,
                                                  const float* __restrict__ fb1,
                                                  float* __restrict__ wsf) {
    __shared__ unsigned int xs[32][100];
    __shared__ __align__(16) float pb[32 * 120];
    __shared__ float bv[16];
    unsigned int* wsu = (unsigned int*)wsf;
    float* p3 = wsf + OFF_P3;
    int tid = threadIdx.x;
    size_t row0 = (size_t)blockIdx.x * 32;
    float s1, s2;
    get_qrelu_scales(wsu, 3, s1, s2);      // conv2-output qrelu scales
    float sp1, sp2;
    get_qrelu_scales(wsu, 1, sp1, sp2);
    float seff2 = sp2 * wsf[10];           // conv2 isum -> preact scale
    float seff = s2 * wsf[11];             // fc1 isum -> preact scale
    if (tid < 16) bv[tid] = b2[tid];
    __syncthreads();
    // fused quant3: read conv2 isum (i16), qrelu to codes, pack into LDS
    {
        const short* isum2 = (const short*)(wsu + OFF_ISUM2);
        for (int i = tid; i < 3200; i += 256) {
            int r = i / 100, w = i % 100;
            const short* sp = isum2 + (row0 + r) * 400 + w * 4;
            unsigned int u = 0;
            #pragma unroll
            for (int k = 0; k < 4; k++) {
                int p = w * 4 + k;
                int code = qrelu_code(fmaf(seff2, (float)sp[k], bv[p / 25]), s1, s2);
                u |= ((unsigned)(code & 255)) << (8 * k);
            }
            xs[r][w] = u;
        }
    }
    __syncthreads();
    float vmax = -INFINITY, vnmax = -INFINITY;
    if (tid < 240) {
        int g = tid / 120, j = tid % 120;
        int acc[16];
        #pragma unroll
        for (int r = 0; r < 16; r++) acc[r] = 0;
        const uint4* wrow = (const uint4*)&wsu[OFF_FQ1 + j * 100];
        for (int kg = 0; kg < 25; kg++) {
            uint4 wv = wrow[kg];
            #pragma unroll
            for (int r = 0; r < 16; r++) {
                uint4 xv = *(const uint4*)&xs[g * 16 + r][kg * 4];
                acc[r] = sdot4(xv.x, wv.x, acc[r]);
                acc[r] = sdot4(xv.y, wv.y, acc[r]);
                acc[r] = sdot4(xv.z, wv.z, acc[r]);
                acc[r] = sdot4(xv.w, wv.w, acc[r]);
            }
        }
        float bias = fb1[j];
        #pragma unroll
        for (int r = 0; r < 16; r++) {
            float pv = fmaf(seff, (float)acc[r], bias);
            pb[(g * 16 + r) * 120 + j] = pv;
            vmax = fmaxf(vmax, pv); vnmax = fmaxf(vnmax, -pv);
        }
    }
    __syncthreads();
    {
        const float4* pb4 = (const float4*)pb;
        float4* d4 = (float4*)(p3 + row0 * 120);
        for (int i = tid; i < 960; i += 256) d4[i] = pb4[i];
    }
    blockAtomicMax2(vmax, vnmax, wsu + 5, wsu + 6);
}

// ---------------- fc2: 256 threads, 48 rows/block ----------------
__global__ __launch_bounds__(256) void fc2_kernel(const float* __restrict__ fb2,
                                                  float* __restrict__ wsf) {
    __shared__ unsigned int xs[48][32];
    __shared__ __align__(16) float pb[48 * 84];
    unsigned int* wsu = (unsigned int*)wsf;
    const float* p3 = wsf + OFF_P3;
    float* p4 = wsf + OFF_P4;
    int tid = threadIdx.x;
    size_t row0 = (size_t)blockIdx.x * 48;
    int nrow = min(48, (int)(BATCH - row0));
    float s1, s2;
    get_qrelu_scales(wsu, 5, s1, s2);
    float seff = s2 * wsf[12];
    const float4* src = (const float4*)(p3 + row0 * 120);
    for (int i = tid; i < nrow * 30; i += 256) {
        float4 v = src[i];
        int c0 = qrelu_code(v.x, s1, s2), c1 = qrelu_code(v.y, s1, s2);
        int c2 = qrelu_code(v.z, s1, s2), c3 = qrelu_code(v.w, s1, s2);
        xs[i / 30][i % 30] = c0 | (c1 << 8) | (c2 << 16) | ((unsigned)c3 << 24);
    }
    if (tid < 48) { xs[tid][30] = 0; xs[tid][31] = 0; }
    __syncthreads();
    float vmax = -INFINITY, vnmax = -INFINITY;
    if (tid < 252) {
        int g = tid / 84, j = tid % 84;
        int acc[16];
        #pragma unroll
        for (int r = 0; r < 16; r++) acc[r] = 0;
        const uint4* wrow = (const uint4*)&wsu[OFF_FQ2 + j * 32];
        #pragma unroll
        for (int kg = 0; kg < 8; kg++) {
            uint4 wv = wrow[kg];
            #pragma unroll
            for (int r = 0; r < 16; r++) {
                uint4 xv = *(const uint4*)&xs[g * 16 + r][kg * 4];
                acc[r] = sdot4(xv.x, wv.x, acc[r]);
                acc[r] = sdot4(xv.y, wv.y, acc[r]);
                acc[r] = sdot4(xv.z, wv.z, acc[r]);
                acc[r] = sdot4(xv.w, wv.w, acc[r]);
            }
        }
        float bias = fb2[j];
        #pragma unroll
        for (int r = 0; r < 16; r++) {
            int lr = g * 16 + r;
            if (lr < nrow) {
                float pv = fmaf(seff, (float)acc[r], bias);
                pb[lr * 84 + j] = pv;
                vmax = fmaxf(vmax, pv); vnmax = fmaxf(vnmax, -pv);
            }
        }
    }
    __syncthreads();
    {
        const float4* pb4 = (const float4*)pb;
        float4* d4 = (float4*)(p4 + row0 * 84);
        for (int i = tid; i < nrow * 21; i += 256) d4[i] = pb4[i];
    }
    blockAtomicMax2(vmax, vnmax, wsu + 7, wsu + 8);
}

// ---------------- fc3 ----------------
__global__ __launch_bounds__(256) void fc3_kernel(const float* __restrict__ fb3,
                                                  float* __restrict__ out,
                                                  float* __restrict__ wsf) {
    __shared__ unsigned int wsm[240];
    __shared__ float bs[10];
    __shared__ __align__(16) float pb[2560];
    unsigned int* wsu = (unsigned int*)wsf;
    const float* p4 = wsf + OFF_P4;
    int tid = threadIdx.x;
    for (int i = tid; i < 240; i += 256) wsm[i] = wsu[OFF_FQ3 + i];
    if (tid < 10) bs[tid] = fb3[tid];
    __syncthreads();
    float s1, s2;
    get_qrelu_scales(wsu, 7, s1, s2);
    float seff = s2 * wsf[13];
    size_t row = (size_t)blockIdx.x * 256 + tid;
    unsigned int xr[24];
    const float4* src = (const float4*)(p4 + row * 84);
    #pragma unroll
    for (int k = 0; k < 21; k++) {
        float4 v = src[k];
        int c0 = qrelu_code(v.x, s1, s2), c1 = qrelu_code(v.y, s1, s2);
        int c2 = qrelu_code(v.z, s1, s2), c3 = qrelu_code(v.w, s1, s2);
        xr[k] = c0 | (c1 << 8) | (c2 << 16) | ((unsigned)c3 << 24);
    }
    xr[21] = 0; xr[22] = 0; xr[23] = 0;
    #pragma unroll
    for (int j = 0; j < 10; j++) {
        int acc = 0;
        #pragma unroll
        for (int k = 0; k < 24; k++) acc = sdot4(xr[k], wsm[j * 24 + k], acc);
        pb[tid * 10 + j] = fmaf(seff, (float)acc, bs[j]);
    }
    __syncthreads();
    {
        const float4* pb4 = (const float4*)pb;
        float4* d4 = (float4*)(out + (size_t)blockIdx.x * 2560);
        for (int i = tid; i < 640; i += 256) d4[i] = pb4[i];
    }
}

extern "C" void kernel_launch(void* const* d_in, const int* in_sizes, int n_in,
                              void* d_out, int out_size, void* d_ws, size_t ws_size,
                              hipStream_t stream) {
    const float* input = (const float*)d_in[0];
    const float* w1  = (const float*)d_in[1];
    const float* b1  = (const float*)d_in[2];
    const float* w2  = (const float*)d_in[3];
    const float* b2  = (const float*)d_in[4];
    const float* fw1 = (const float*)d_in[5];
    const float* fb1 = (const float*)d_in[6];
    const float* fw2 = (const float*)d_in[7];
    const float* fb2 = (const float*)d_in[8];
    const float* fw3 = (const float*)d_in[9];
    const float* fb3 = (const float*)d_in[10];
    float* ws  = (float*)d_ws;
    float* out = (float*)d_out;

    prep_kernel<<<6, 256, 0, stream>>>(w1, w2, fw1, fw2, fw3, ws);
    absmax_kernel<<<2048, 256, 0, stream>>>((const float4*)input,
                                            (int)((size_t)BATCH * 3072 / 4),
                                            (unsigned int*)ws);
    quant1_kernel<<<8192, 256, 0, stream>>>((const float4*)input, ws);
    conv1_kernel<<<BATCH / C1_NIMG, 256, 0, stream>>>(b1, ws);
    conv2_kernel<<<(BATCH + C2_NIMG - 1) / C2_NIMG, 256, 0, stream>>>(b1, b2, ws);
    fc1_kernel<<<BATCH / 32, 256, 0, stream>>>(b2, fb1, ws);
    fc2_kernel<<<(BATCH + 47) / 48, 256, 0, stream>>>(fb2, ws);
    fc3_kernel<<<BATCH / 256, 256, 0, stream>>>(fb3, out, ws);
}

// Round 18
// 466.906 us; speedup vs baseline: 1.0417x; 1.0417x over previous
//
#include <hip/hip_runtime.h>
#include <math.h>

#define BATCH 16384
#define EPSQ 1e-8f

// ---------------- ws layout (32-bit units) ----------------
#define OFF_SCAL 0
#define OFF_WPK1 16        // 180 u32
#define OFF_WPK2 196       // 960 u32
#define OFF_FQ1  1156      // 12000 u32
#define OFF_FQ2  13156     // 2688 u32
#define OFF_FQ3  15844     // 240 u32
#define OFF_A    16384
#define OFF_QIN   OFF_A                 // [B][3][32slots][48] i8 quant1->conv1
#define OFF_QC2   OFF_A                 // [B][6][16slots][16] i8 quant2->conv2
#define OFF_ISUM2 (OFF_A + 6400000)     // [B][400] i16 conv2->quant3
#define OFF_QC3   (OFF_A + 10000000)    // [B][100] u32 quant3->fc1
#define OFF_P3    (OFF_A + 12000000)    // [B][120] f32 fc1->fc2
#define OFF_P4    (OFF_A + 14000000)    // [B][84]  f32 fc2->fc3
#define OFF_ISUM1 (OFF_A + 18874368)    // [B][1176] i16 conv1->quant2

__device__ inline int sdot4(unsigned int a, unsigned int b, int c) {
    return __builtin_amdgcn_sdot4((int)a, (int)b, c, false);
}

__device__ inline unsigned int fkey(float f) {
    unsigned int u = __float_as_uint(f);
    return (u & 0x80000000u) ? ~u : (u | 0x80000000u);
}
__device__ inline float fdec(unsigned int k) {
    unsigned int u = (k & 0x80000000u) ? (k ^ 0x80000000u) : ~k;
    return __uint_as_float(u);
}
#define KEY_ZERO   0x80000000u
#define KEY_NEGINF 0x007FFFFFu

__device__ inline float waveMax(float v) {
    #pragma unroll
    for (int off = 32; off > 0; off >>= 1)
        v = fmaxf(v, __shfl_down(v, off, 64));
    return v;
}

__device__ inline void blockAtomicMax2(float vmax, float vnmax,
                                       unsigned int* gmax, unsigned int* gnmax) {
    __shared__ float sm[4], sn[4];
    float a = waveMax(vmax), b = waveMax(vnmax);
    int tid = threadIdx.x;
    if ((tid & 63) == 0) { sm[tid >> 6] = a; sn[tid >> 6] = b; }
    __syncthreads();
    if (tid == 0) {
        atomicMax(gmax, fkey(fmaxf(fmaxf(sm[0], sm[1]), fmaxf(sm[2], sm[3]))));
        atomicMax(gnmax, fkey(fmaxf(fmaxf(sn[0], sn[1]), fmaxf(sn[2], sn[3]))));
    }
}

__device__ inline float fq_elem(float x, float s) {
    float q = fminf(fmaxf(rintf(x / s), -128.0f), 127.0f);
    return q * s;
}
__device__ inline int qrelu_code(float x, float s1, float s2) {
    float q = fq_elem(x, s1);
    q = fmaxf(q, 0.0f);
    return (int)fminf(fmaxf(rintf(q / s2), -128.0f), 127.0f);
}
__device__ inline void get_qrelu_scales(const unsigned int* scalu, int slot,
                                        float& s1, float& s2) {
    float maxa = fdec(scalu[slot]), negm = fdec(scalu[slot + 1]);
    float absm = fmaxf(maxa, negm);
    s1 = fmaxf(absm / 127.0f, EPSQ);
    float qm = fminf(fmaxf(rintf(maxa / s1), -128.0f), 127.0f) * s1;
    s2 = fmaxf(fmaxf(qm, 0.0f) / 127.0f, EPSQ);
}

__device__ inline unsigned int sgn8(float w) { return (w >= 0.0f) ? 0x01u : 0xFFu; }

__device__ inline unsigned int u32at(const unsigned int* wv, int wi, int k) {
    return (k == 0) ? wv[wi]
        : __builtin_amdgcn_perm(wv[wi + 1], wv[wi], 0x03020100u + 0x01010101u * (unsigned)k);
}

// ---------------- prep ----------------
__global__ __launch_bounds__(256) void prep_kernel(const float* __restrict__ w1,
        const float* __restrict__ w2, const float* __restrict__ fw1,
        const float* __restrict__ fw2, const float* __restrict__ fw3,
        float* __restrict__ wsf) {
    int blk = blockIdx.x, tid = threadIdx.x;
    unsigned int* wsu = (unsigned int*)wsf;
    if (blk == 0) {
        if (tid == 0) wsu[0] = KEY_ZERO;
        else if (tid <= 8) wsu[tid] = KEY_NEGINF;
        return;
    }
    const float* src = nullptr; int N = 0;
    if (blk == 1)      { src = w1;  N = 450; }
    else if (blk == 2) { src = w2;  N = 2400; }
    else if (blk == 3) { src = fw1; N = 48000; }
    else if (blk == 4) { src = fw2; N = 10080; }
    else               { src = fw3; N = 840; }
    __shared__ float red[256];
    float partial = 0.0f;
    for (int i = tid; i < N; i += 256) partial += fabsf(src[i]);
    red[tid] = partial;
    __syncthreads();
    for (int s = 128; s > 0; s >>= 1) {
        if (tid < s) red[tid] += red[tid + s];
        __syncthreads();
    }
    if (tid == 0) wsf[8 + blk] = red[0] / (float)N;

    if (blk == 1) {
        for (int t = tid; t < 90; t += 256) {
            const float* wp = w1 + t * 5;
            wsu[OFF_WPK1 + 2*t] = sgn8(wp[0]) | (sgn8(wp[1])<<8) | (sgn8(wp[2])<<16) | (sgn8(wp[3])<<24);
            wsu[OFF_WPK1 + 2*t + 1] = sgn8(wp[4]) << 24;
        }
    } else if (blk == 2) {
        for (int t = tid; t < 480; t += 256) {
            const float* wp = w2 + t * 5;
            wsu[OFF_WPK2 + 2*t] = sgn8(wp[0]) | (sgn8(wp[1])<<8) | (sgn8(wp[2])<<16) | (sgn8(wp[3])<<24);
            wsu[OFF_WPK2 + 2*t + 1] = sgn8(wp[4]) << 24;
        }
    } else if (blk == 3) {
        for (int i = tid; i < 12000; i += 256) {
            int j = i / 100, k = i % 100;
            const float* wp = fw1 + j * 400 + k * 4;
            wsu[OFF_FQ1 + i] = sgn8(wp[0]) | (sgn8(wp[1])<<8) | (sgn8(wp[2])<<16) | (sgn8(wp[3])<<24);
        }
    } else if (blk == 4) {
        for (int i = tid; i < 2688; i += 256) {
            int j = i >> 5, k = i & 31;
            unsigned int u = 0;
            if (k < 30) {
                const float* wp = fw2 + j * 120 + k * 4;
                u = sgn8(wp[0]) | (sgn8(wp[1])<<8) | (sgn8(wp[2])<<16) | (sgn8(wp[3])<<24);
            }
            wsu[OFF_FQ2 + i] = u;
        }
    } else {
        for (int i = tid; i < 240; i += 256) {
            int j = i / 24, k = i % 24;
            unsigned int u = 0;
            if (k < 21) {
                const float* wp = fw3 + j * 84 + k * 4;
                u = sgn8(wp[0]) | (sgn8(wp[1])<<8) | (sgn8(wp[2])<<16) | (sgn8(wp[3])<<24);
            }
            wsu[OFF_FQ3 + i] = u;
        }
    }
}

// ---------------- input abs-max ----------------
__global__ __launch_bounds__(256) void absmax_kernel(const float4* __restrict__ x, int n4,
                                                     unsigned int* __restrict__ gkey) {
    float m = 0.0f;
    int stride = gridDim.x * 256;
    for (int i = blockIdx.x * 256 + threadIdx.x; i < n4; i += stride) {
        float4 v = x[i];
        m = fmaxf(m, fmaxf(fmaxf(fabsf(v.x), fabsf(v.y)), fmaxf(fabsf(v.z), fabsf(v.w))));
    }
    __shared__ float sm[4];
    m = waveMax(m);
    int tid = threadIdx.x;
    if ((tid & 63) == 0) sm[tid >> 6] = m;
    __syncthreads();
    if (tid == 0)
        atomicMax(gkey, fkey(fmaxf(fmaxf(sm[0], sm[1]), fmaxf(sm[2], sm[3]))));
}

// ---------------- quant1: fp32 -> i8 codes, row-interleaved [B][3][slot(32)][48] ----
__global__ __launch_bounds__(256) void quant1_kernel(const float4* __restrict__ x,
                                                     float* __restrict__ wsf) {
    unsigned int* wsu = (unsigned int*)wsf;
    float s0 = fmaxf(fdec(wsu[0]) / 127.0f, EPSQ);
    unsigned int* qin = wsu + OFF_QIN;
    int stride = gridDim.x * 256;
    const int total = BATCH * 96 * 12;
    for (int unit = blockIdx.x * 256 + threadIdx.x; unit < total; unit += stride) {
        int row_id = unit / 12, w = unit % 12;
        int plane = row_id >> 5, row = row_id & 31;
        int slot = (row >> 1) + ((row & 1) << 4);
        unsigned int u = 0;
        if (w < 8) {
            float4 v = x[row_id * 8 + w];
            int q0 = (int)fminf(fmaxf(rintf(v.x / s0), -128.f), 127.f);
            int q1 = (int)fminf(fmaxf(rintf(v.y / s0), -128.f), 127.f);
            int q2 = (int)fminf(fmaxf(rintf(v.z / s0), -128.f), 127.f);
            int q3 = (int)fminf(fmaxf(rintf(v.w / s0), -128.f), 127.f);
            u = (q0 & 255) | ((q1 & 255) << 8) | ((q2 & 255) << 16) | ((unsigned)(q3 & 255) << 24);
        }
        qin[(plane * 32 + slot) * 12 + w] = u;
    }
}

// ---------------- conv1: 9 img/block, thread = (img, c-triple, py), dot4 ------
#define C1_ROWP 48
#define C1_CIS  1536
#define C1_IMGS 4608
#define C1_NIMG 9

template<int PH>
__device__ __forceinline__ void c1_phase3(const unsigned char* ib, const unsigned int* wcp,
                                          int ip[3][7], int gmax[3], int gmin[3]) {
    int a0[3][14], a1[3][14];
    #pragma unroll
    for (int cc = 0; cc < 3; cc++)
        #pragma unroll
        for (int i = 0; i < 14; i++) { a0[cc][i] = 0; a1[cc][i] = 0; }
    #pragma unroll 1
    for (int ci = 0; ci < 3; ci++) {
        uint4 A[6]; unsigned int Bv[6];
        const unsigned char* cb = ib + ci * C1_CIS;
        #pragma unroll
        for (int r = 0; r < 6; r++) {
            const unsigned char* rb = cb + (((r & 1) << 4) + (r >> 1)) * C1_ROWP;
            if (PH == 0) {
                A[r]  = *(const uint4*)(rb);
                Bv[r] = *(const unsigned int*)(rb + 16);
            } else {
                Bv[r] = *(const unsigned int*)(rb + 12);
                A[r]  = *(const uint4*)(rb + 16);
            }
        }
        #pragma unroll
        for (int r6 = 0; r6 < 6; r6++) {
            unsigned int wv[5];
            if (PH == 0) {
                wv[0] = A[r6].x; wv[1] = A[r6].y; wv[2] = A[r6].z; wv[3] = A[r6].w; wv[4] = Bv[r6];
            } else {
                wv[0] = Bv[r6]; wv[1] = A[r6].x; wv[2] = A[r6].y; wv[3] = A[r6].z; wv[4] = A[r6].w;
            }
            const int OFS = (PH == 0) ? 0 : 2;
            unsigned int up[15];
            #pragma unroll
            for (int i = 0; i < 15; i++) {
                int e = OFS + i;
                up[i] = u32at(wv, e >> 2, e & 3);
            }
            #pragma unroll
            for (int cc = 0; cc < 3; cc++) {
                const unsigned int* wkp = wcp + cc * 30 + ci * 10;
                if (r6 <= 4) {
                    unsigned int w0 = wkp[2 * r6], w4 = wkp[2 * r6 + 1];
                    #pragma unroll
                    for (int i = 0; i < 14; i++) {
                        a0[cc][i] = sdot4(up[i], w0, a0[cc][i]);
                        a0[cc][i] = sdot4(up[i + 1], w4, a0[cc][i]);
                    }
                }
                if (r6 >= 1) {
                    unsigned int w0 = wkp[2 * (r6 - 1)], w4 = wkp[2 * (r6 - 1) + 1];
                    #pragma unroll
                    for (int i = 0; i < 14; i++) {
                        a1[cc][i] = sdot4(up[i], w0, a1[cc][i]);
                        a1[cc][i] = sdot4(up[i + 1], w4, a1[cc][i]);
                    }
                }
            }
        }
    }
    #pragma unroll
    for (int cc = 0; cc < 3; cc++) {
        #pragma unroll
        for (int i = 0; i < 14; i++) {
            gmax[cc] = max(gmax[cc], max(a0[cc][i], a1[cc][i]));
            gmin[cc] = min(gmin[cc], min(a0[cc][i], a1[cc][i]));
        }
        #pragma unroll
        for (int p = 0; p < 7; p++)
            ip[cc][p] = max(max(a0[cc][2*p], a0[cc][2*p+1]), max(a1[cc][2*p], a1[cc][2*p+1]));
    }
}

__global__ __launch_bounds__(256) void conv1_kernel(const float* __restrict__ b1,
                                                    float* __restrict__ wsf) {
    __shared__ __align__(16) unsigned char xq[C1_NIMG * C1_IMGS];   // 41472 B
    __shared__ unsigned int wpk[180];
    __shared__ float bsm[6];
    unsigned int* wsu = (unsigned int*)wsf;
    int tid = threadIdx.x;
    int b0 = blockIdx.x * C1_NIMG;
    int nimg = min(C1_NIMG, BATCH - b0);
    float s0 = fmaxf(fdec(wsu[0]) / 127.0f, EPSQ);
    float seff = s0 * wsf[9];

    {
        const uint4* src = (const uint4*)((const unsigned char*)(wsu + OFF_QIN) + (size_t)b0 * C1_IMGS);
        uint4* dst = (uint4*)xq;
        for (int i = tid; i < nimg * 288; i += 256) dst[i] = src[i];
    }
    for (int i = tid; i < 180; i += 256) wpk[i] = wsu[OFF_WPK1 + i];
    if (tid < 6) bsm[tid] = b1[tid];
    __syncthreads();

    unsigned int* isum1 = wsu + OFF_ISUM1;
    float vmax = -INFINITY, vnmax = -INFINITY;
    int ntask = nimg * 28;   // (img, chalf, py): <= 252
    if (tid < ntask) {
        int img = tid / 28, rem = tid % 28;
        int chalf = rem / 14, py = rem % 14;
        int c0 = chalf * 3;
        const unsigned char* ib = &xq[img * C1_IMGS + py * C1_ROWP];
        const unsigned int* wcp = &wpk[c0 * 30];
        int ip0[3][7], ip1[3][7];
        int gmax[3] = {-2000000000, -2000000000, -2000000000};
        int gmin[3] = { 2000000000,  2000000000,  2000000000};
        c1_phase3<0>(ib, wcp, ip0, gmax, gmin);
        c1_phase3<1>(ib, wcp, ip1, gmax, gmin);
        #pragma unroll
        for (int cc = 0; cc < 3; cc++) {
            float bias = bsm[c0 + cc];
            vmax  = fmaxf(vmax,  fmaf(seff, (float)gmax[cc], bias));
            vnmax = fmaxf(vnmax, -fmaf(seff, (float)gmin[cc], bias));
            unsigned int* dst = isum1 + 588 * (size_t)(b0 + img) + 7 * ((c0 + cc) * 14 + py);
            int v14[14];
            #pragma unroll
            for (int p = 0; p < 7; p++) { v14[p] = ip0[cc][p]; v14[7 + p] = ip1[cc][p]; }
            #pragma unroll
            for (int p = 0; p < 7; p++)
                dst[p] = (v14[2*p] & 0xFFFF) | ((unsigned)(v14[2*p+1] & 0xFFFF) << 16);
        }
    }
    blockAtomicMax2(vmax, vnmax, wsu + 1, wsu + 2);
}

// ---------------- quant2 ----------------
__global__ __launch_bounds__(256) void quant2_kernel(const float* __restrict__ b1,
                                                     float* __restrict__ wsf) {
    unsigned int* wsu = (unsigned int*)wsf;
    float s1, s2;
    get_qrelu_scales(wsu, 1, s1, s2);
    float s0 = fmaxf(fdec(wsu[0]) / 127.0f, EPSQ);
    float seff = s0 * wsf[9];
    float bv[6];
    #pragma unroll
    for (int c = 0; c < 6; c++) bv[c] = b1[c];
    const short* isum1 = (const short*)(wsu + OFF_ISUM1);
    unsigned int* qc2 = wsu + OFF_QC2;
    int stride = gridDim.x * 256;
    const int total = BATCH * 84 * 4;
    for (int unit = blockIdx.x * 256 + threadIdx.x; unit < total; unit += stride) {
        int row_id = unit >> 2, w = unit & 3;
        int bci = row_id / 14, row = row_id % 14;
        int ci = bci % 6;
        int slot = (row >> 1) + ((row & 1) << 3);
        float bias = bv[ci];
        unsigned int u = 0;
        const short* sp = isum1 + (size_t)bci * 196 + row * 14;
        #pragma unroll
        for (int k = 0; k < 4; k++) {
            int col = w * 4 + k;
            int code = 0;
            if (col < 14) {
                float pre = fmaf(seff, (float)sp[col], bias);
                code = qrelu_code(pre, s1, s2);
            }
            u |= ((unsigned)(code & 255)) << (8 * k);
        }
        qc2[((size_t)bci * 16 + slot) * 4 + w] = u;
    }
}

// ---------------- conv2: 12 img/block, thread = (img, c-quad, py), dot4 ------
#define C2_ROWP 16
#define C2_CIS  256
#define C2_IMGS 1536
#define C2_NIMG 12

__global__ __launch_bounds__(256) void conv2_kernel(const float* __restrict__ b2,
                                                    float* __restrict__ wsf) {
    __shared__ __align__(16) unsigned char act[C2_NIMG * C2_IMGS];  // 18432 B
    __shared__ unsigned int wpk[960];
    __shared__ float bsm[16];
    __shared__ __align__(16) short spb[C2_NIMG * 400];               // 9600 B
    unsigned int* wsu = (unsigned int*)wsf;
    int tid = threadIdx.x;
    int b0 = blockIdx.x * C2_NIMG;
    int nimg = min(C2_NIMG, BATCH - b0);
    float s1, s2;
    get_qrelu_scales(wsu, 1, s1, s2);
    float seff = s2 * wsf[10];

    {
        const uint4* src = (const uint4*)((const unsigned char*)(wsu + OFF_QC2) + (size_t)b0 * C2_IMGS);
        uint4* dst = (uint4*)act;
        for (int i = tid; i < nimg * 96; i += 256) dst[i] = src[i];
    }
    for (int i = tid; i < 960; i += 256) wpk[i] = wsu[OFF_WPK2 + i];
    if (tid < 16) bsm[tid] = b2[tid];
    __syncthreads();

    float vmax = -INFINITY, vnmax = -INFINITY;
    int ntask = nimg * 20;
    if (tid < ntask) {
        int img = tid / 20, rem = tid % 20;
        int cq = rem / 5, py = rem % 5;
        int c0 = cq * 4;
        const unsigned char* ib = &act[img * C2_IMGS + py * C2_ROWP];
        int a0[4][10], a1[4][10];
        #pragma unroll
        for (int cc = 0; cc < 4; cc++)
            #pragma unroll
            for (int i = 0; i < 10; i++) { a0[cc][i] = 0; a1[cc][i] = 0; }
        #pragma unroll 1
        for (int ci = 0; ci < 6; ci++) {
            uint4 R[6];
            #pragma unroll
            for (int r6 = 0; r6 < 6; r6++)
                R[r6] = *(const uint4*)(ib + ci * C2_CIS + (((r6 & 1) << 3) + (r6 >> 1)) * C2_ROWP);
            #pragma unroll
            for (int r6 = 0; r6 < 6; r6++) {
                unsigned int wv[4] = { R[r6].x, R[r6].y, R[r6].z, R[r6].w };
                unsigned int up[11];
                #pragma unroll
                for (int i = 0; i < 11; i++) up[i] = u32at(wv, i >> 2, i & 3);
                #pragma unroll
                for (int cc = 0; cc < 4; cc++) {
                    const unsigned int* wkp = &wpk[((c0 + cc) * 6 + ci) * 10];
                    if (r6 <= 4) {
                        unsigned int w0 = wkp[2 * r6], w4 = wkp[2 * r6 + 1];
                        #pragma unroll
                        for (int i = 0; i < 10; i++) {
                            a0[cc][i] = sdot4(up[i], w0, a0[cc][i]);
                            a0[cc][i] = sdot4(up[i + 1], w4, a0[cc][i]);
                        }
                    }
                    if (r6 >= 1) {
                        unsigned int w0 = wkp[2 * (r6 - 1)], w4 = wkp[2 * (r6 - 1) + 1];
                        #pragma unroll
                        for (int i = 0; i < 10; i++) {
                            a1[cc][i] = sdot4(up[i], w0, a1[cc][i]);
                            a1[cc][i] = sdot4(up[i + 1], w4, a1[cc][i]);
                        }
                    }
                }
            }
        }
        #pragma unroll
        for (int cc = 0; cc < 4; cc++) {
            int gmax = -2000000000, gmin = 2000000000;
            #pragma unroll
            for (int i = 0; i < 10; i++) {
                gmax = max(gmax, max(a0[cc][i], a1[cc][i]));
                gmin = min(gmin, min(a0[cc][i], a1[cc][i]));
            }
            float bias = bsm[c0 + cc];
            vmax  = fmaxf(vmax,  fmaf(seff, (float)gmax, bias));
            vnmax = fmaxf(vnmax, -fmaf(seff, (float)gmin, bias));
            short* dst = spb + img * 400 + (c0 + cc) * 25 + py * 5;
            #pragma unroll
            for (int p = 0; p < 5; p++)
                dst[p] = (short)max(max(a0[cc][2*p], a0[cc][2*p+1]),
                                    max(a1[cc][2*p], a1[cc][2*p+1]));
        }
    }
    __syncthreads();
    {
        const uint4* pb4 = (const uint4*)spb;
        uint4* d4 = (uint4*)((short*)(wsu + OFF_ISUM2) + (size_t)b0 * 400);
        for (int i = tid; i < nimg * 50; i += 256) d4[i] = pb4[i];
    }
    blockAtomicMax2(vmax, vnmax, wsu + 3, wsu + 4);
}

// ---------------- quant3 ----------------
__global__ __launch_bounds__(256) void quant3_kernel(const float* __restrict__ b2,
                                                     float* __restrict__ wsf) {
    unsigned int* wsu = (unsigned int*)wsf;
    float s1, s2;
    get_qrelu_scales(wsu, 3, s1, s2);
    float sp1, sp2;
    get_qrelu_scales(wsu, 1, sp1, sp2);
    float seff = sp2 * wsf[10];
    __shared__ float bv[16];
    if (threadIdx.x < 16) bv[threadIdx.x] = b2[threadIdx.x];
    __syncthreads();
    const short* isum2 = (const short*)(wsu + OFF_ISUM2);
    unsigned int* qc3 = wsu + OFF_QC3;
    int stride = gridDim.x * 256;
    const int total = BATCH * 100;
    for (int unit = blockIdx.x * 256 + threadIdx.x; unit < total; unit += stride) {
        int b = unit / 100, w = unit % 100;
        const short* sp = isum2 + (size_t)b * 400 + w * 4;
        unsigned int u = 0;
        #pragma unroll
        for (int k = 0; k < 4; k++) {
            int p = w * 4 + k;
            float pre = fmaf(seff, (float)sp[k], bv[p / 25]);
            int code = qrelu_code(pre, s1, s2);
            u |= ((unsigned)(code & 255)) << (8 * k);
        }
        qc3[unit] = u;
    }
}

// ---------------- fc1: 256 threads, 32 rows/block (512 blocks) ----------------
__global__ __launch_bounds__(256) void fc1_kernel(const float* __restrict__ fb1,
                                                  float* __restrict__ wsf) {
    __shared__ unsigned int xs[32][100];
    __shared__ __align__(16) float pb[32 * 120];
    unsigned int* wsu = (unsigned int*)wsf;
    float* p3 = wsf + OFF_P3;
    int tid = threadIdx.x;
    size_t row0 = (size_t)blockIdx.x * 32;
    float s1, s2;
    get_qrelu_scales(wsu, 3, s1, s2);
    float seff = s2 * wsf[11];
    {
        const uint4* src = (const uint4*)(wsu + OFF_QC3 + row0 * 100);
        uint4* dst = (uint4*)xs;
        for (int i = tid; i < 800; i += 256) dst[i] = src[i];
    }
    __syncthreads();
    float vmax = -INFINITY, vnmax = -INFINITY;
    if (tid < 240) {
        int g = tid / 120, j = tid % 120;
        int acc[16];
        #pragma unroll
        for (int r = 0; r < 16; r++) acc[r] = 0;
        const uint4* wrow = (const uint4*)&wsu[OFF_FQ1 + j * 100];
        for (int kg = 0; kg < 25; kg++) {
            uint4 wv = wrow[kg];
            #pragma unroll
            for (int r = 0; r < 16; r++) {
                uint4 xv = *(const uint4*)&xs[g * 16 + r][kg * 4];
                acc[r] = sdot4(xv.x, wv.x, acc[r]);
                acc[r] = sdot4(xv.y, wv.y, acc[r]);
                acc[r] = sdot4(xv.z, wv.z, acc[r]);
                acc[r] = sdot4(xv.w, wv.w, acc[r]);
            }
        }
        float bias = fb1[j];
        #pragma unroll
        for (int r = 0; r < 16; r++) {
            float pv = fmaf(seff, (float)acc[r], bias);
            pb[(g * 16 + r) * 120 + j] = pv;
            vmax = fmaxf(vmax, pv); vnmax = fmaxf(vnmax, -pv);
        }
    }
    __syncthreads();
    {
        const float4* pb4 = (const float4*)pb;
        float4* d4 = (float4*)(p3 + row0 * 120);
        for (int i = tid; i < 960; i += 256) d4[i] = pb4[i];
    }
    blockAtomicMax2(vmax, vnmax, wsu + 5, wsu + 6);
}

// ---------------- fc2: 256 threads, 48 rows/block ----------------
__global__ __launch_bounds__(256) void fc2_kernel(const float* __restrict__ fb2,
                                                  float* __restrict__ wsf) {
    __shared__ unsigned int xs[48][32];
    __shared__ __align__(16) float pb[48 * 84];
    unsigned int* wsu = (unsigned int*)wsf;
    const float* p3 = wsf + OFF_P3;
    float* p4 = wsf + OFF_P4;
    int tid = threadIdx.x;
    size_t row0 = (size_t)blockIdx.x * 48;
    int nrow = min(48, (int)(BATCH - row0));
    float s1, s2;
    get_qrelu_scales(wsu, 5, s1, s2);
    float seff = s2 * wsf[12];
    const float4* src = (const float4*)(p3 + row0 * 120);
    for (int i = tid; i < nrow * 30; i += 256) {
        float4 v = src[i];
        int c0 = qrelu_code(v.x, s1, s2), c1 = qrelu_code(v.y, s1, s2);
        int c2 = qrelu_code(v.z, s1, s2), c3 = qrelu_code(v.w, s1, s2);
        xs[i / 30][i % 30] = c0 | (c1 << 8) | (c2 << 16) | ((unsigned)c3 << 24);
    }
    if (tid < 48) { xs[tid][30] = 0; xs[tid][31] = 0; }
    __syncthreads();
    float vmax = -INFINITY, vnmax = -INFINITY;
    if (tid < 252) {
        int g = tid / 84, j = tid % 84;
        int acc[16];
        #pragma unroll
        for (int r = 0; r < 16; r++) acc[r] = 0;
        const uint4* wrow = (const uint4*)&wsu[OFF_FQ2 + j * 32];
        #pragma unroll
        for (int kg = 0; kg < 8; kg++) {
            uint4 wv = wrow[kg];
            #pragma unroll
            for (int r = 0; r < 16; r++) {
                uint4 xv = *(const uint4*)&xs[g * 16 + r][kg * 4];
                acc[r] = sdot4(xv.x, wv.x, acc[r]);
                acc[r] = sdot4(xv.y, wv.y, acc[r]);
                acc[r] = sdot4(xv.z, wv.z, acc[r]);
                acc[r] = sdot4(xv.w, wv.w, acc[r]);
            }
        }
        float bias = fb2[j];
        #pragma unroll
        for (int r = 0; r < 16; r++) {
            int lr = g * 16 + r;
            if (lr < nrow) {
                float pv = fmaf(seff, (float)acc[r], bias);
                pb[lr * 84 + j] = pv;
                vmax = fmaxf(vmax, pv); vnmax = fmaxf(vnmax, -pv);
            }
        }
    }
    __syncthreads();
    {
        const float4* pb4 = (const float4*)pb;
        float4* d4 = (float4*)(p4 + row0 * 84);
        for (int i = tid; i < nrow * 21; i += 256) d4[i] = pb4[i];
    }
    blockAtomicMax2(vmax, vnmax, wsu + 7, wsu + 8);
}

// ---------------- fc3 ----------------
__global__ __launch_bounds__(256) void fc3_kernel(const float* __restrict__ fb3,
                                                  float* __restrict__ out,
                                                  float* __restrict__ wsf) {
    __shared__ unsigned int wsm[240];
    __shared__ float bs[10];
    __shared__ __align__(16) float pb[2560];
    unsigned int* wsu = (unsigned int*)wsf;
    const float* p4 = wsf + OFF_P4;
    int tid = threadIdx.x;
    for (int i = tid; i < 240; i += 256) wsm[i] = wsu[OFF_FQ3 + i];
    if (tid < 10) bs[tid] = fb3[tid];
    __syncthreads();
    float s1, s2;
    get_qrelu_scales(wsu, 7, s1, s2);
    float seff = s2 * wsf[13];
    size_t row = (size_t)blockIdx.x * 256 + tid;
    unsigned int xr[24];
    const float4* src = (const float4*)(p4 + row * 84);
    #pragma unroll
    for (int k = 0; k < 21; k++) {
        float4 v = src[k];
        int c0 = qrelu_code(v.x, s1, s2), c1 = qrelu_code(v.y, s1, s2);
        int c2 = qrelu_code(v.z, s1, s2), c3 = qrelu_code(v.w, s1, s2);
        xr[k] = c0 | (c1 << 8) | (c2 << 16) | ((unsigned)c3 << 24);
    }
    xr[21] = 0; xr[22] = 0; xr[23] = 0;
    #pragma unroll
    for (int j = 0; j < 10; j++) {
        int acc = 0;
        #pragma unroll
        for (int k = 0; k < 24; k++) acc = sdot4(xr[k], wsm[j * 24 + k], acc);
        pb[tid * 10 + j] = fmaf(seff, (float)acc, bs[j]);
    }
    __syncthreads();
    {
        const float4* pb4 = (const float4*)pb;
        float4* d4 = (float4*)(out + (size_t)blockIdx.x * 2560);
        for (int i = tid; i < 640; i += 256) d4[i] = pb4[i];
    }
}

extern "C" void kernel_launch(void* const* d_in, const int* in_sizes, int n_in,
                              void* d_out, int out_size, void* d_ws, size_t ws_size,
                              hipStream_t stream) {
    const float* input = (const float*)d_in[0];
    const float* w1  = (const float*)d_in[1];
    const float* b1  = (const float*)d_in[2];
    const float* w2  = (const float*)d_in[3];
    const float* b2  = (const float*)d_in[4];
    const float* fw1 = (const float*)d_in[5];
    const float* fb1 = (const float*)d_in[6];
    const float* fw2 = (const float*)d_in[7];
    const float* fb2 = (const float*)d_in[8];
    const float* fw3 = (const float*)d_in[9];
    const float* fb3 = (const float*)d_in[10];
    float* ws  = (float*)d_ws;
    float* out = (float*)d_out;

    prep_kernel<<<6, 256, 0, stream>>>(w1, w2, fw1, fw2, fw3, ws);
    absmax_kernel<<<2048, 256, 0, stream>>>((const float4*)input,
                                            (int)((size_t)BATCH * 3072 / 4),
                                            (unsigned int*)ws);
    quant1_kernel<<<8192, 256, 0, stream>>>((const float4*)input, ws);
    conv1_kernel<<<(BATCH + C1_NIMG - 1) / C1_NIMG, 256, 0, stream>>>(b1, ws);
    quant2_kernel<<<4096, 256, 0, stream>>>(b1, ws);
    conv2_kernel<<<(BATCH + C2_NIMG - 1) / C2_NIMG, 256, 0, stream>>>(b2, ws);
    quant3_kernel<<<2048, 256, 0, stream>>>(b2, ws);
    fc1_kernel<<<BATCH / 32, 256, 0, stream>>>(fb1, ws);
    fc2_kernel<<<(BATCH + 47) / 48, 256, 0, stream>>>(fb2, ws);
    fc3_kernel<<<BATCH / 256, 256, 0, stream>>>(fb3, out, ws);
}